// Round 7
// baseline (172.367 us; speedup 1.0000x reference)
//
#include <hip/hip_runtime.h>
#include <hip/hip_bf16.h>
#include <math.h>

typedef __attribute__((ext_vector_type(8))) short bf16x8;
typedef __attribute__((ext_vector_type(4))) float f32x4;

#define NQ 16384
#define NN 32
#define FI 128
#define FO 256
#define KPN 15
#define OD 42
#define INV_EXT 0.5f

// ws layout (bytes)
#define WS_FP1    0u                        // [NQ][64] uint2 {hi(fA)|hi(fB), lo(fA)|lo(fB)} = 8 MB
#define WS_FP2    (8u * 1024u * 1024u)      // [NQ][64]  u32 fp-interleaved hi-pairs = 4 MB
#define WS_BSW    (12u * 1024u * 1024u)     // 1 MB
#define WS_DWBH   (13u * 1024u * 1024u)     // 196,608
#define WS_DWBL   (WS_DWBH + 196608u)       // 196,608
#define WS_DEFKP  (14u * 1024u * 1024u)     // 16384*45*4 = 2.95 MB

static __device__ __forceinline__ unsigned short f2bf(float x) {
    union { __hip_bfloat16 h; unsigned short u; } cv;
    cv.h = __float2bfloat16(x);
    return cv.u;
}
static __device__ __forceinline__ float bf2f(unsigned short h) {
    union { unsigned int u; float f; } cv;
    cv.u = ((unsigned int)h) << 16;
    return cv.f;
}

union U8 { unsigned short u[8]; bf16x8 v; };

// ------------------------- pre-kernel (vectorized, unchanged from R6) -------------------------
__global__ void pre_all(const float* __restrict__ feat,
                        unsigned int* __restrict__ fp1, unsigned int* __restrict__ fp2,
                        const float* __restrict__ w, unsigned short* __restrict__ Bsw,
                        const float* __restrict__ dw,
                        unsigned short* __restrict__ dhi, unsigned short* __restrict__ dlo)
{
    const int b = blockIdx.x, t = threadIdx.x;
    if (b < 1024) {
        const int g  = b * 256 + t;           // 262,144 = 16384 * 4fp * 4lq
        const int lq = g & 3;
        const int fp = (g >> 2) & 3;
        const int s  = g >> 4;
        const float4* f4 = (const float4*)feat;
        const float4 A = f4[s * 32 + fp * 8 + lq];       // f = fp*32 + lq*4 + e
        const float4 C = f4[s * 32 + fp * 8 + 4 + lq];   // f + 16
        const float av[4] = {A.x, A.y, A.z, A.w};
        const float cv[4] = {C.x, C.y, C.z, C.w};
        unsigned int pw[8];
        #pragma unroll
        for (int e = 0; e < 4; e++) {
            const unsigned short ha = f2bf(av[e]), hc = f2bf(cv[e]);
            const unsigned short la = f2bf(av[e] - bf2f(ha));
            const unsigned short lc = f2bf(cv[e] - bf2f(hc));
            pw[2 * e]     = (unsigned int)ha | ((unsigned int)hc << 16);
            pw[2 * e + 1] = (unsigned int)la | ((unsigned int)lc << 16);
            fp2[s * 64 + (fp >> 1) * 32 + (lq * 4 + e) * 2 + (fp & 1)] =
                (unsigned int)ha | ((unsigned int)hc << 16);
        }
        *(uint4*)&fp1[s * 128 + fp * 32 + lq * 8]     = *(uint4*)&pw[0];
        *(uint4*)&fp1[s * 128 + fp * 32 + lq * 8 + 4] = *(uint4*)&pw[4];
    } else if (b < 1024 + 256) {
        const int tid = (b - 1024) * 256 + t; // 65536 total
        const int lane = tid & 63;
        const int kt   = (tid >> 6) & 63;
        const int nt   = tid >> 12;
        const int n    = nt * 16 + (lane & 15);
        const int kbase = kt * 32 + (lane >> 4) * 8;
        unsigned int p[4];
        #pragma unroll
        for (int jj = 0; jj < 4; jj++) {
            unsigned int lo, hi;
            {
                const int kk = kbase + 2 * jj;
                const int f = kk >> 4, k = kk & 15;
                lo = (k < KPN) ? f2bf(w[(k * FI + f) * FO + n]) : 0u;
            }
            {
                const int kk = kbase + 2 * jj + 1;
                const int f = kk >> 4, k = kk & 15;
                hi = (k < KPN) ? f2bf(w[(k * FI + f) * FO + n]) : 0u;
            }
            p[jj] = lo | (hi << 16);
        }
        unsigned int* op = (unsigned int*)&Bsw[tid * 8];
        op[0] = p[0]; op[1] = p[1]; op[2] = p[2]; op[3] = p[3];
    } else {
        const int tid = (b - 1280) * 256 + t; // 12288 total
        const int lane = tid & 63;
        const int kt   = (tid >> 6) & 63;
        const int nt   = tid >> 12;
        const int o    = nt * 16 + (lane & 15);
        const int kbase = kt * 32 + (lane >> 4) * 8;
        #pragma unroll
        for (int j = 0; j < 8; j++) {
            const int kf = kbase + j;
            const int f = kf >> 4, k = kf & 15;
            float v = (k < KPN && o < OD) ? dw[(k * FI + f) * OD + o] : 0.f;
            unsigned short h = f2bf(v);
            dhi[tid * 8 + j] = h;
            dlo[tid * 8 + j] = f2bf(v - bf2f(h));
        }
    }
}

// ------------------------- stage 1: offsets, 2-deep chunk pipeline -------------------------
// E=16, 512 threads. LDS ~75.2 KB -> 2 blocks/CU. Per chunk c:
//   ISSUE gathers(c+1) -> phase-C(c) (MFMA + dwB L2 loads cover gather latency)
//   -> BUILD(c+1) into wf[(c+1)&1] -> ONE barrier. (R6: 2 barriers/chunk, no overlap.)
// wf layout per 32-f chunk: cblk = fc + (k>>3)*32, slot = e ^ (fc&15),
//   hw = cblk*128 + slot*8 + (k&7). Reads: each bank exactly 2x (free). Writes 2-way (free).
__global__ __launch_bounds__(512, 4)
void k1_offsets(const float* __restrict__ query, const float* __restrict__ support,
                const int* __restrict__ neighbors, const unsigned int* __restrict__ fp1,
                const float* __restrict__ kpoints,
                const unsigned short* __restrict__ dwB_hi,
                const unsigned short* __restrict__ dwB_lo,
                const float* __restrict__ bias, float* __restrict__ defkp)
{
    __shared__ unsigned short wf_hi[2][8192];           // 32 KB
    __shared__ unsigned short wf_lo[2][8192];           // 32 KB
    __shared__ float relx[512], rely[512], relz[512];   // 6 KB
    __shared__ int   nbr_s[512];                        // 2 KB
    __shared__ float kp_s[48];                          // 192 B
    __shared__ f32x4 cred[3 * 64];                      // 3 KB

    const int t = threadIdx.x;
    const int qbase = blockIdx.x * 16;
    if (t < 45) kp_s[t] = kpoints[t];
    if (t >= 45 && t < 48) kp_s[t] = 0.f;

    {   // 512 threads = 16 queries x 32 neighbors
        const int e = t >> 5, n = t & 31;
        const int q = qbase + e;
        const int idx = neighbors[q * NN + n];
        nbr_s[t] = idx;
        relx[t] = support[idx * 3 + 0] - query[q * 3 + 0];
        rely[t] = support[idx * 3 + 1] - query[q * 3 + 1];
        relz[t] = support[idx * 3 + 2] - query[q * 3 + 2];
    }
    __syncthreads();

    const int wave = t >> 6, lane = t & 63;
    const int quad = lane >> 4, low = lane & 15;
    const int kb = (low < KPN) ? low * 3 : 0;

    // A-fragments (split-bf16 w0^T), 2 queries per wave
    U8 ah[2], al[2];
    {
        const float kx = kp_s[kb + 0], ky = kp_s[kb + 1], kz = kp_s[kb + 2];
        #pragma unroll
        for (int ei = 0; ei < 2; ei++) {
            const int ee = wave * 2 + ei;
            #pragma unroll
            for (int j = 0; j < 8; j++) {
                const int ni = ee * 32 + quad * 8 + j;
                const float dx = relx[ni] - kx;
                const float dy = rely[ni] - ky;
                const float dz = relz[ni] - kz;
                const float d = sqrtf(dx * dx + dy * dy + dz * dz);
                float w = 1.0f - d * INV_EXT;
                w = (low < KPN && w > 0.f) ? w : 0.f;
                const unsigned short h = f2bf(w);
                ah[ei].u[j] = h;
                al[ei].u[j] = f2bf(w - bf2f(h));
            }
        }
    }

    f32x4 acc = {0.f, 0.f, 0.f, 0.f};
    const int nt = wave >> 1, half = wave & 1;   // phase-C: 3 o-tiles x 2 slice-halves
    const uint2* fp1v = (const uint2*)fp1;
    const bf16x8* Bh = (const bf16x8*)dwB_hi;
    const bf16x8* Bl = (const bf16x8*)dwB_lo;

    uint2 g[2][4][2];    // prefetched gathers: [ei][jj][r0/r1] = 16 uint2 (static-indexed)

    // ---- macros: static-index loops only (rule #20) ----
#define K1_ISSUE(CC)                                                          \
    _Pragma("unroll")                                                         \
    for (int ei = 0; ei < 2; ei++) {                                          \
        const int ee = wave * 2 + ei;                                         \
        _Pragma("unroll")                                                     \
        for (int jj = 0; jj < 4; jj++) {                                      \
            const int r0 = nbr_s[ee * 32 + quad * 8 + 2 * jj];                \
            const int r1 = nbr_s[ee * 32 + quad * 8 + 2 * jj + 1];            \
            g[ei][jj][0] = fp1v[r0 * 64 + (CC) * 16 + low];                   \
            g[ei][jj][1] = fp1v[r1 * 64 + (CC) * 16 + low];                   \
        }                                                                     \
    }

#define K1_BUILD(CC)                                                          \
    _Pragma("unroll")                                                         \
    for (int ei = 0; ei < 2; ei++) {                                          \
        const int ee = wave * 2 + ei;                                         \
        union { unsigned int u[4]; bf16x8 v; } bhA, blA, bhB, blB;            \
        _Pragma("unroll")                                                     \
        for (int jj = 0; jj < 4; jj++) {                                      \
            const uint2 d0 = g[ei][jj][0];                                    \
            const uint2 d1 = g[ei][jj][1];                                    \
            bhA.u[jj] = __builtin_amdgcn_perm(d1.x, d0.x, 0x05040100u);       \
            bhB.u[jj] = __builtin_amdgcn_perm(d1.x, d0.x, 0x07060302u);       \
            blA.u[jj] = __builtin_amdgcn_perm(d1.y, d0.y, 0x05040100u);       \
            blB.u[jj] = __builtin_amdgcn_perm(d1.y, d0.y, 0x07060302u);       \
        }                                                                     \
        _Pragma("unroll")                                                     \
        for (int hh2 = 0; hh2 < 2; hh2++) {                                   \
            const bf16x8 bh = hh2 ? bhB.v : bhA.v;                            \
            const bf16x8 bl = hh2 ? blB.v : blA.v;                            \
            f32x4 o = {0.f, 0.f, 0.f, 0.f};                                   \
            o = __builtin_amdgcn_mfma_f32_16x16x32_bf16(al[ei].v, bh, o, 0, 0, 0); \
            o = __builtin_amdgcn_mfma_f32_16x16x32_bf16(ah[ei].v, bl, o, 0, 0, 0); \
            o = __builtin_amdgcn_mfma_f32_16x16x32_bf16(ah[ei].v, bh, o, 0, 0, 0); \
            const int fc   = hh2 * 16 + low;                                  \
            const int cblk = fc + (quad >> 1) * 32;                           \
            const int slot = ee ^ (fc & 15);                                  \
            const int hw   = cblk * 128 + slot * 8 + (quad & 1) * 4;          \
            const unsigned short h0 = f2bf(o[0]), h1 = f2bf(o[1]);            \
            const unsigned short h2 = f2bf(o[2]), h3 = f2bf(o[3]);            \
            uint2 ph;                                                         \
            ph.x = (unsigned int)h0 | ((unsigned int)h1 << 16);               \
            ph.y = (unsigned int)h2 | ((unsigned int)h3 << 16);               \
            *(uint2*)&wf_hi[(CC) & 1][hw] = ph;                               \
            uint2 pl;                                                         \
            pl.x = (unsigned int)f2bf(o[0] - bf2f(h0)) |                      \
                   ((unsigned int)f2bf(o[1] - bf2f(h1)) << 16);               \
            pl.y = (unsigned int)f2bf(o[2] - bf2f(h2)) |                      \
                   ((unsigned int)f2bf(o[3] - bf2f(h3)) << 16);               \
            *(uint2*)&wf_lo[(CC) & 1][hw] = pl;                               \
        }                                                                     \
    }

    // prologue: fill buffer 0
    K1_ISSUE(0)
    K1_BUILD(0)
    __syncthreads();

    for (int c = 0; c < 4; c++) {
        if (c < 3) { K1_ISSUE(c + 1) }            // prefetch next chunk's gathers
        if (wave < 6) {
            // ---- phase C: feat0[16e x 48o] accumulate from wf[c&1] ----
            #pragma unroll 4
            for (int ktl = half * 8; ktl < half * 8 + 8; ktl++) {
                const int fc   = ktl * 2 + (quad >> 1);
                const int cblk = fc + (quad & 1) * 32;        // k>>3 = quad&1
                const int slot = low ^ (fc & 15);
                const int hw   = cblk * 128 + slot * 8;
                bf16x8 a_h = *(const bf16x8*)&wf_hi[c & 1][hw];
                bf16x8 a_l = *(const bf16x8*)&wf_lo[c & 1][hw];
                const int ktg = c * 16 + ktl;
                bf16x8 b_h = Bh[(nt * 64 + ktg) * 64 + lane];
                bf16x8 b_l = Bl[(nt * 64 + ktg) * 64 + lane];
                acc = __builtin_amdgcn_mfma_f32_16x16x32_bf16(a_l, b_h, acc, 0, 0, 0);
                acc = __builtin_amdgcn_mfma_f32_16x16x32_bf16(a_h, b_l, acc, 0, 0, 0);
                acc = __builtin_amdgcn_mfma_f32_16x16x32_bf16(a_h, b_h, acc, 0, 0, 0);
            }
        } else if (c == 0 && wave == 6 && lane < 48) {
            defkp[(qbase + lane / 3) * 45 + (lane % 3)] = kp_s[lane % 3];
        }
        if (c < 3) { K1_BUILD(c + 1) }            // consume prefetched gathers
        __syncthreads();
    }

    if (wave < 6 && half == 1) cred[nt * 64 + lane] = acc;
    __syncthreads();
    if (wave < 6 && half == 0) {
        f32x4 o2 = cred[nt * 64 + lane];
        acc[0] += o2[0]; acc[1] += o2[1]; acc[2] += o2[2]; acc[3] += o2[3];
        const int o = nt * 16 + low;
        if (o < OD) {
            const float bo = bias[o] + kp_s[3 + o];
            #pragma unroll
            for (int r = 0; r < 4; r++) {
                const int ee = quad * 4 + r;
                defkp[(qbase + ee) * 45 + 3 + o] = bo + acc[r];
            }
        }
    }
#undef K1_ISSUE
#undef K1_BUILD
}

// ------------------------- stage 2: deformable conv (unchanged from R6) -------------------------
__global__ __launch_bounds__(512, 4)
void k2_deform(const float* __restrict__ query, const float* __restrict__ support,
               const int* __restrict__ neighbors, const unsigned int* __restrict__ fp2,
               const unsigned short* __restrict__ Bsw, const float* __restrict__ defkp,
               float* __restrict__ out)
{
    __shared__ unsigned short wf2[32768];                 // 64 KB (aliased below)
    __shared__ unsigned short nbr_s[1024];                // 2 KB

    float* relx = (float*)wf2;          // [0,1024)      4 KB
    float* rely = relx + 1024;          // [1024,2048)   4 KB
    float* relz = relx + 2048;          // [2048,3072)   4 KB
    float* dk_s = relx + 3072;          // [3072,4512)   5.76 KB  (all dead after prologue)

    const int t = threadIdx.x;
    const int qbase = blockIdx.x * 32;

    for (int i = t; i < 32 * 45; i += 512) dk_s[i] = defkp[qbase * 45 + i];
    #pragma unroll
    for (int ii = 0; ii < 2; ii++) {
        const int i = ii * 512 + t;
        const int e = i >> 5, n = i & 31;
        const int q = qbase + e;
        const int idx = neighbors[q * NN + n];
        nbr_s[i] = (unsigned short)idx;
        relx[i] = support[idx * 3 + 0] - query[q * 3 + 0];
        rely[i] = support[idx * 3 + 1] - query[q * 3 + 1];
        relz[i] = support[idx * 3 + 2] - query[q * 3 + 2];
    }
    __syncthreads();

    const int wave = t >> 6, lane = t & 63;
    const int quad = lane >> 4, low = lane & 15;
    const int kb = (low < KPN) ? low * 3 : 0;

    // A-fragments (plain bf16 w1^T), 4 queries per wave — consumes rel/dk
    U8 af[4];
    #pragma unroll
    for (int ei = 0; ei < 4; ei++) {
        const int ee = wave * 4 + ei;
        const float kx = dk_s[ee * 45 + kb + 0];
        const float ky = dk_s[ee * 45 + kb + 1];
        const float kz = dk_s[ee * 45 + kb + 2];
        #pragma unroll
        for (int j = 0; j < 8; j++) {
            const int ni = ee * 32 + quad * 8 + j;
            const float dx = relx[ni] - kx;
            const float dy = rely[ni] - ky;
            const float dz = relz[ni] - kz;
            const float d = sqrtf(dx * dx + dy * dy + dz * dz);
            float w = 1.0f - d * INV_EXT;
            w = (low < KPN && w > 0.f) ? w : 0.f;
            af[ei].u[j] = f2bf(w);
        }
    }
    __syncthreads();   // rel/dk dead; wf2 free for tiles

    f32x4 acc00 = {0,0,0,0}, acc01 = {0,0,0,0};
    f32x4 acc10 = {0,0,0,0}, acc11 = {0,0,0,0};
    const int nt0 = wave * 2, nt1 = nt0 + 1;
    const bf16x8* Bp = (const bf16x8*)Bsw;
    const uint2* fp2v = (const uint2*)fp2;

    for (int c2 = 0; c2 < 2; c2++) {
        // ---- build BOTH chunk tiles from one uint2 gather per line ----
        #pragma unroll
        for (int ei = 0; ei < 4; ei++) {
            const int ee = wave * 4 + ei;
            union { unsigned int u[4]; bf16x8 v; } b00, b01, b10, b11; // [p][hh2]
            #pragma unroll
            for (int jj = 0; jj < 4; jj++) {
                const int r0 = nbr_s[ee * 32 + quad * 8 + 2 * jj];
                const int r1 = nbr_s[ee * 32 + quad * 8 + 2 * jj + 1];
                const uint2 g0 = fp2v[r0 * 32 + c2 * 16 + low];
                const uint2 g1 = fp2v[r1 * 32 + c2 * 16 + low];
                b00.u[jj] = __builtin_amdgcn_perm(g1.x, g0.x, 0x05040100u); // p=0, fA
                b01.u[jj] = __builtin_amdgcn_perm(g1.x, g0.x, 0x07060302u); // p=0, fB
                b10.u[jj] = __builtin_amdgcn_perm(g1.y, g0.y, 0x05040100u); // p=1, fA
                b11.u[jj] = __builtin_amdgcn_perm(g1.y, g0.y, 0x07060302u); // p=1, fB
            }
            #pragma unroll
            for (int p = 0; p < 2; p++) {
                #pragma unroll
                for (int hh2 = 0; hh2 < 2; hh2++) {
                    const bf16x8 b = p ? (hh2 ? b11.v : b10.v)
                                       : (hh2 ? b01.v : b00.v);
                    f32x4 o = {0.f, 0.f, 0.f, 0.f};
                    o = __builtin_amdgcn_mfma_f32_16x16x32_bf16(af[ei].v, b, o, 0, 0, 0);
                    const int fc   = hh2 * 16 + low;
                    const int cblk = fc + (quad >> 1) * 32;   // k>>3 = quad>>1
                    const int slot = ee ^ fc;
                    const int hw   = p * 16384 + cblk * 256 + slot * 8 + (quad & 1) * 4;
                    uint2 ph;
                    ph.x = (unsigned int)f2bf(o[0]) | ((unsigned int)f2bf(o[1]) << 16);
                    ph.y = (unsigned int)f2bf(o[2]) | ((unsigned int)f2bf(o[3]) << 16);
                    *(uint2*)&wf2[hw] = ph;
                }
            }
        }
        __syncthreads();
        // ---- GEMM over both chunks: out[32 x 256] += wf1 * Bsw ----
        #pragma unroll
        for (int p = 0; p < 2; p++) {
            #pragma unroll 4
            for (int ktl = 0; ktl < 16; ktl++) {
                const int fc   = ktl * 2 + (quad >> 1);
                const int cblk = fc + (quad & 1) * 32;        // k>>3 = quad&1
                const int s0 = (low ^ fc) * 8;
                const int s1 = ((16 + low) ^ fc) * 8;
                bf16x8 a0 = *(const bf16x8*)&wf2[p * 16384 + cblk * 256 + s0];
                bf16x8 a1 = *(const bf16x8*)&wf2[p * 16384 + cblk * 256 + s1];
                const int ktg = (2 * c2 + p) * 16 + ktl;
                bf16x8 b0 = Bp[(nt0 * 64 + ktg) * 64 + lane];
                bf16x8 b1 = Bp[(nt1 * 64 + ktg) * 64 + lane];
                acc00 = __builtin_amdgcn_mfma_f32_16x16x32_bf16(a0, b0, acc00, 0, 0, 0);
                acc01 = __builtin_amdgcn_mfma_f32_16x16x32_bf16(a0, b1, acc01, 0, 0, 0);
                acc10 = __builtin_amdgcn_mfma_f32_16x16x32_bf16(a1, b0, acc10, 0, 0, 0);
                acc11 = __builtin_amdgcn_mfma_f32_16x16x32_bf16(a1, b1, acc11, 0, 0, 0);
            }
        }
        __syncthreads();
    }

    #pragma unroll
    for (int r = 0; r < 4; r++) {
        const int e0 = quad * 4 + r;
        out[(qbase + e0) * FO + nt0 * 16 + low] = acc00[r];
        out[(qbase + e0) * FO + nt1 * 16 + low] = acc01[r];
        out[(qbase + 16 + e0) * FO + nt0 * 16 + low] = acc10[r];
        out[(qbase + 16 + e0) * FO + nt1 * 16 + low] = acc11[r];
    }
}

// -------------------------------------------------------------------------
extern "C" void kernel_launch(void* const* d_in, const int* in_sizes, int n_in,
                              void* d_out, int out_size, void* d_ws, size_t ws_size,
                              hipStream_t stream) {
    const float* query     = (const float*)d_in[0];
    const float* support   = (const float*)d_in[1];
    const int*   neighbors = (const int*)  d_in[2];
    const float* features  = (const float*)d_in[3];
    const float* kpoints   = (const float*)d_in[4];
    const float* weight    = (const float*)d_in[5];
    const float* dweight   = (const float*)d_in[6];
    const float* bias      = (const float*)d_in[7];
    float*       out       = (float*)d_out;

    char* ws = (char*)d_ws;
    unsigned int*   fp1  = (unsigned int*)(ws + WS_FP1);
    unsigned int*   fp2  = (unsigned int*)(ws + WS_FP2);
    unsigned short* Bsw  = (unsigned short*)(ws + WS_BSW);
    unsigned short* dwBh = (unsigned short*)(ws + WS_DWBH);
    unsigned short* dwBl = (unsigned short*)(ws + WS_DWBL);
    float*          defkp = (float*)(ws + WS_DEFKP);

    pre_all<<<1328, 256, 0, stream>>>(features, fp1, fp2, weight, Bsw,
                                      dweight, dwBh, dwBl);
    k1_offsets<<<NQ / 16, 512, 0, stream>>>(query, support, neighbors, fp1,
                                            kpoints, dwBh, dwBl, bias, defkp);
    k2_deform<<<NQ / 32, 512, 0, stream>>>(query, support, neighbors, fp2,
                                           Bsw, defkp, out);
}

// Round 8
// 163.905 us; speedup vs baseline: 1.0516x; 1.0516x over previous
//
#include <hip/hip_runtime.h>
#include <hip/hip_bf16.h>
#include <math.h>

typedef __attribute__((ext_vector_type(8))) short bf16x8;
typedef __attribute__((ext_vector_type(4))) float f32x4;

#define NQ 16384
#define NN 32
#define FI 128
#define FO 256
#define KPN 15
#define OD 42
#define INV_EXT 0.5f

// ws layout (bytes)
#define WS_FP1    0u                        // [NQ][64] uint2 {hi(fA)|hi(fB), lo(fA)|lo(fB)} = 8 MB
#define WS_FP2    (8u * 1024u * 1024u)      // [NQ][64]  u32 fp-interleaved hi-pairs = 4 MB
#define WS_BSW    (12u * 1024u * 1024u)     // 1 MB
#define WS_DWBH   (13u * 1024u * 1024u)     // 196,608
#define WS_DWBL   (WS_DWBH + 196608u)       // 196,608
#define WS_DEFKP  (14u * 1024u * 1024u)     // 16384*45*4 = 2.95 MB

static __device__ __forceinline__ unsigned short f2bf(float x) {
    union { __hip_bfloat16 h; unsigned short u; } cv;
    cv.h = __float2bfloat16(x);
    return cv.u;
}
static __device__ __forceinline__ float bf2f(unsigned short h) {
    union { unsigned int u; float f; } cv;
    cv.u = ((unsigned int)h) << 16;
    return cv.f;
}

union U8 { unsigned short u[8]; bf16x8 v; };

// ------------------------- pre-kernel (vectorized, unchanged from R6) -------------------------
__global__ void pre_all(const float* __restrict__ feat,
                        unsigned int* __restrict__ fp1, unsigned int* __restrict__ fp2,
                        const float* __restrict__ w, unsigned short* __restrict__ Bsw,
                        const float* __restrict__ dw,
                        unsigned short* __restrict__ dhi, unsigned short* __restrict__ dlo)
{
    const int b = blockIdx.x, t = threadIdx.x;
    if (b < 1024) {
        const int g  = b * 256 + t;           // 262,144 = 16384 * 4fp * 4lq
        const int lq = g & 3;
        const int fp = (g >> 2) & 3;
        const int s  = g >> 4;
        const float4* f4 = (const float4*)feat;
        const float4 A = f4[s * 32 + fp * 8 + lq];       // f = fp*32 + lq*4 + e
        const float4 C = f4[s * 32 + fp * 8 + 4 + lq];   // f + 16
        const float av[4] = {A.x, A.y, A.z, A.w};
        const float cv[4] = {C.x, C.y, C.z, C.w};
        unsigned int pw[8];
        #pragma unroll
        for (int e = 0; e < 4; e++) {
            const unsigned short ha = f2bf(av[e]), hc = f2bf(cv[e]);
            const unsigned short la = f2bf(av[e] - bf2f(ha));
            const unsigned short lc = f2bf(cv[e] - bf2f(hc));
            pw[2 * e]     = (unsigned int)ha | ((unsigned int)hc << 16);
            pw[2 * e + 1] = (unsigned int)la | ((unsigned int)lc << 16);
            fp2[s * 64 + (fp >> 1) * 32 + (lq * 4 + e) * 2 + (fp & 1)] =
                (unsigned int)ha | ((unsigned int)hc << 16);
        }
        *(uint4*)&fp1[s * 128 + fp * 32 + lq * 8]     = *(uint4*)&pw[0];
        *(uint4*)&fp1[s * 128 + fp * 32 + lq * 8 + 4] = *(uint4*)&pw[4];
    } else if (b < 1024 + 256) {
        const int tid = (b - 1024) * 256 + t; // 65536 total
        const int lane = tid & 63;
        const int kt   = (tid >> 6) & 63;
        const int nt   = tid >> 12;
        const int n    = nt * 16 + (lane & 15);
        const int kbase = kt * 32 + (lane >> 4) * 8;
        unsigned int p[4];
        #pragma unroll
        for (int jj = 0; jj < 4; jj++) {
            unsigned int lo, hi;
            {
                const int kk = kbase + 2 * jj;
                const int f = kk >> 4, k = kk & 15;
                lo = (k < KPN) ? f2bf(w[(k * FI + f) * FO + n]) : 0u;
            }
            {
                const int kk = kbase + 2 * jj + 1;
                const int f = kk >> 4, k = kk & 15;
                hi = (k < KPN) ? f2bf(w[(k * FI + f) * FO + n]) : 0u;
            }
            p[jj] = lo | (hi << 16);
        }
        unsigned int* op = (unsigned int*)&Bsw[tid * 8];
        op[0] = p[0]; op[1] = p[1]; op[2] = p[2]; op[3] = p[3];
    } else {
        const int tid = (b - 1280) * 256 + t; // 12288 total
        const int lane = tid & 63;
        const int kt   = (tid >> 6) & 63;
        const int nt   = tid >> 12;
        const int o    = nt * 16 + (lane & 15);
        const int kbase = kt * 32 + (lane >> 4) * 8;
        #pragma unroll
        for (int j = 0; j < 8; j++) {
            const int kf = kbase + j;
            const int f = kf >> 4, k = kf & 15;
            float v = (k < KPN && o < OD) ? dw[(k * FI + f) * OD + o] : 0.f;
            unsigned short h = f2bf(v);
            dhi[tid * 8 + j] = h;
            dlo[tid * 8 + j] = f2bf(v - bf2f(h));
        }
    }
}

// ------------------------- stage 1: offsets (R6 exact — measured 49.9 us) -------------------------
// LDS ~43.5 KB -> 3 blocks/CU. Conflict-free swizzle; latency-bound structural floor ~50 us
// (VALU floor ~19 us; 2-blocks/CU alternatives measured worse in R2/R7).
__global__ __launch_bounds__(512, 4)
void k1_offsets(const float* __restrict__ query, const float* __restrict__ support,
                const int* __restrict__ neighbors, const unsigned int* __restrict__ fp1,
                const float* __restrict__ kpoints,
                const unsigned short* __restrict__ dwB_hi,
                const unsigned short* __restrict__ dwB_lo,
                const float* __restrict__ bias, float* __restrict__ defkp)
{
    __shared__ unsigned short wf_hi[8192];              // 16 KB
    __shared__ unsigned short wf_lo[8192];              // 16 KB
    __shared__ float relx[512], rely[512], relz[512];   // 6 KB
    __shared__ int   nbr_s[512];                        // 2 KB
    __shared__ float kp_s[48];                          // 192 B
    __shared__ f32x4 cred[3 * 64];                      // 3 KB

    const int t = threadIdx.x;
    const int qbase = blockIdx.x * 16;
    if (t < 45) kp_s[t] = kpoints[t];
    if (t >= 45 && t < 48) kp_s[t] = 0.f;

    {   // 512 threads = 16 queries x 32 neighbors
        const int e = t >> 5, n = t & 31;
        const int q = qbase + e;
        const int idx = neighbors[q * NN + n];
        nbr_s[t] = idx;
        relx[t] = support[idx * 3 + 0] - query[q * 3 + 0];
        rely[t] = support[idx * 3 + 1] - query[q * 3 + 1];
        relz[t] = support[idx * 3 + 2] - query[q * 3 + 2];
    }
    __syncthreads();

    const int wave = t >> 6, lane = t & 63;
    const int quad = lane >> 4, low = lane & 15;
    const int kb = (low < KPN) ? low * 3 : 0;

    // A-fragments (split-bf16 w0^T), 2 queries per wave
    U8 ah[2], al[2];
    {
        const float kx = kp_s[kb + 0], ky = kp_s[kb + 1], kz = kp_s[kb + 2];
        #pragma unroll
        for (int ei = 0; ei < 2; ei++) {
            const int ee = wave * 2 + ei;
            #pragma unroll
            for (int j = 0; j < 8; j++) {
                const int ni = ee * 32 + quad * 8 + j;
                const float dx = relx[ni] - kx;
                const float dy = rely[ni] - ky;
                const float dz = relz[ni] - kz;
                const float d = sqrtf(dx * dx + dy * dy + dz * dz);
                float w = 1.0f - d * INV_EXT;
                w = (low < KPN && w > 0.f) ? w : 0.f;
                const unsigned short h = f2bf(w);
                ah[ei].u[j] = h;
                al[ei].u[j] = f2bf(w - bf2f(h));
            }
        }
    }

    f32x4 acc = {0.f, 0.f, 0.f, 0.f};
    const int nt = wave >> 1, half = wave & 1;   // phase-C: 3 o-tiles x 2 slice-halves
    const uint2* fp1v = (const uint2*)fp1;
    const bf16x8* Bh = (const bf16x8*)dwB_hi;
    const bf16x8* Bl = (const bf16x8*)dwB_lo;

    for (int c = 0; c < 4; c++) {
        // ---- phase B: wf0 chunk (split hi/lo) ----
        #pragma unroll
        for (int ei = 0; ei < 2; ei++) {
            const int ee = wave * 2 + ei;
            union { unsigned int u[4]; bf16x8 v; } bhA, blA, bhB, blB;
            #pragma unroll
            for (int jj = 0; jj < 4; jj++) {
                const int r0 = nbr_s[ee * 32 + quad * 8 + 2 * jj];
                const int r1 = nbr_s[ee * 32 + quad * 8 + 2 * jj + 1];
                const uint2 d0 = fp1v[r0 * 64 + c * 16 + low];
                const uint2 d1 = fp1v[r1 * 64 + c * 16 + low];
                bhA.u[jj] = __builtin_amdgcn_perm(d1.x, d0.x, 0x05040100u);
                bhB.u[jj] = __builtin_amdgcn_perm(d1.x, d0.x, 0x07060302u);
                blA.u[jj] = __builtin_amdgcn_perm(d1.y, d0.y, 0x05040100u);
                blB.u[jj] = __builtin_amdgcn_perm(d1.y, d0.y, 0x07060302u);
            }
            #pragma unroll
            for (int hh2 = 0; hh2 < 2; hh2++) {
                const bf16x8 bh = hh2 ? bhB.v : bhA.v;
                const bf16x8 bl = hh2 ? blB.v : blA.v;
                f32x4 o = {0.f, 0.f, 0.f, 0.f};
                o = __builtin_amdgcn_mfma_f32_16x16x32_bf16(al[ei].v, bh, o, 0, 0, 0);
                o = __builtin_amdgcn_mfma_f32_16x16x32_bf16(ah[ei].v, bl, o, 0, 0, 0);
                o = __builtin_amdgcn_mfma_f32_16x16x32_bf16(ah[ei].v, bh, o, 0, 0, 0);
                const int fc   = hh2 * 16 + low;              // f within chunk
                const int cblk = fc + (quad >> 1) * 32;       // k>>3 = quad>>1
                const int slot = ee ^ (fc & 15);
                const int hw   = cblk * 128 + slot * 8 + (quad & 1) * 4;
                const unsigned short h0 = f2bf(o[0]), h1 = f2bf(o[1]);
                const unsigned short h2 = f2bf(o[2]), h3 = f2bf(o[3]);
                uint2 ph;
                ph.x = (unsigned int)h0 | ((unsigned int)h1 << 16);
                ph.y = (unsigned int)h2 | ((unsigned int)h3 << 16);
                *(uint2*)&wf_hi[hw] = ph;
                uint2 pl;
                pl.x = (unsigned int)f2bf(o[0] - bf2f(h0)) |
                       ((unsigned int)f2bf(o[1] - bf2f(h1)) << 16);
                pl.y = (unsigned int)f2bf(o[2] - bf2f(h2)) |
                       ((unsigned int)f2bf(o[3] - bf2f(h3)) << 16);
                *(uint2*)&wf_lo[hw] = pl;
            }
        }
        __syncthreads();
        // ---- phase C: feat0[16e x 48o] accumulate (6 waves) ----
        if (wave < 6) {
            #pragma unroll 4
            for (int ktl = half * 8; ktl < half * 8 + 8; ktl++) {
                const int fc   = ktl * 2 + (quad >> 1);
                const int cblk = fc + (quad & 1) * 32;        // k>>3 = quad&1
                const int slot = low ^ (fc & 15);
                const int hw   = cblk * 128 + slot * 8;
                bf16x8 a_h = *(const bf16x8*)&wf_hi[hw];
                bf16x8 a_l = *(const bf16x8*)&wf_lo[hw];
                const int ktg = c * 16 + ktl;
                bf16x8 b_h = Bh[(nt * 64 + ktg) * 64 + lane];
                bf16x8 b_l = Bl[(nt * 64 + ktg) * 64 + lane];
                acc = __builtin_amdgcn_mfma_f32_16x16x32_bf16(a_l, b_h, acc, 0, 0, 0);
                acc = __builtin_amdgcn_mfma_f32_16x16x32_bf16(a_h, b_l, acc, 0, 0, 0);
                acc = __builtin_amdgcn_mfma_f32_16x16x32_bf16(a_h, b_h, acc, 0, 0, 0);
            }
        } else if (c == 0 && wave == 6 && lane < 48) {
            defkp[(qbase + lane / 3) * 45 + (lane % 3)] = kp_s[lane % 3];
        }
        __syncthreads();
    }

    if (wave < 6 && half == 1) cred[nt * 64 + lane] = acc;
    __syncthreads();
    if (wave < 6 && half == 0) {
        f32x4 o2 = cred[nt * 64 + lane];
        acc[0] += o2[0]; acc[1] += o2[1]; acc[2] += o2[2]; acc[3] += o2[3];
        const int o = nt * 16 + low;
        if (o < OD) {
            const float bo = bias[o] + kp_s[3 + o];
            #pragma unroll
            for (int r = 0; r < 4; r++) {
                const int ee = quad * 4 + r;
                defkp[(qbase + ee) * 45 + 3 + o] = bo + acc[r];
            }
        }
    }
}

// ------------------------- stage 2: deformable conv, 1-deep gather pipeline -------------------------
// E=32, 512 threads, LDS 66 KB -> 2 blocks/CU (no block to lose: prefetch is free here).
// Rolling ISSUE(next unit) || BUILD(current unit) with two NAMED register buffers
// (gqA/gqB, static-indexed). First gather issues before the sqrt-heavy A-fragment
// chain; the (ei=0,c2=1) gather rides through GEMM(0) in registers.
// VGPR est ~100 < 128 cap at 4 waves/SIMD.
__global__ __launch_bounds__(512, 4)
void k2_deform(const float* __restrict__ query, const float* __restrict__ support,
               const int* __restrict__ neighbors, const unsigned int* __restrict__ fp2,
               const unsigned short* __restrict__ Bsw, const float* __restrict__ defkp,
               float* __restrict__ out)
{
    __shared__ unsigned short wf2[32768];                 // 64 KB (aliased below)
    __shared__ unsigned short nbr_s[1024];                // 2 KB

    float* relx = (float*)wf2;          // [0,1024)      4 KB
    float* rely = relx + 1024;          // [1024,2048)   4 KB
    float* relz = relx + 2048;          // [2048,3072)   4 KB
    float* dk_s = relx + 3072;          // [3072,4512)   5.76 KB  (all dead after prologue)

    const int t = threadIdx.x;
    const int qbase = blockIdx.x * 32;

    for (int i = t; i < 32 * 45; i += 512) dk_s[i] = defkp[qbase * 45 + i];
    #pragma unroll
    for (int ii = 0; ii < 2; ii++) {
        const int i = ii * 512 + t;
        const int e = i >> 5, n = i & 31;
        const int q = qbase + e;
        const int idx = neighbors[q * NN + n];
        nbr_s[i] = (unsigned short)idx;
        relx[i] = support[idx * 3 + 0] - query[q * 3 + 0];
        rely[i] = support[idx * 3 + 1] - query[q * 3 + 1];
        relz[i] = support[idx * 3 + 2] - query[q * 3 + 2];
    }
    __syncthreads();

    const int wave = t >> 6, lane = t & 63;
    const int quad = lane >> 4, low = lane & 15;
    const int kb = (low < KPN) ? low * 3 : 0;

    const uint2* fp2v = (const uint2*)fp2;
    const bf16x8* Bp = (const bf16x8*)Bsw;
    const int nt0 = wave * 2, nt1 = nt0 + 1;

    uint2 gqA[8], gqB[8];
    U8 af[4];
    f32x4 acc00 = {0,0,0,0}, acc01 = {0,0,0,0};
    f32x4 acc10 = {0,0,0,0}, acc11 = {0,0,0,0};

#define K2_ISSUE(G, EI, C2)                                                   \
    { const int ee_ = wave * 4 + (EI);                                        \
      _Pragma("unroll")                                                       \
      for (int jj = 0; jj < 4; jj++) {                                        \
          const int r0 = nbr_s[ee_ * 32 + quad * 8 + 2 * jj];                 \
          const int r1 = nbr_s[ee_ * 32 + quad * 8 + 2 * jj + 1];             \
          G[2 * jj]     = fp2v[r0 * 32 + (C2) * 16 + low];                    \
          G[2 * jj + 1] = fp2v[r1 * 32 + (C2) * 16 + low];                    \
      } }

#define K2_BUILD(G, EI)                                                       \
    { const int ee_ = wave * 4 + (EI);                                        \
      union { unsigned int u[4]; bf16x8 v; } b00, b01, b10, b11;              \
      _Pragma("unroll")                                                       \
      for (int jj = 0; jj < 4; jj++) {                                        \
          const uint2 g0 = G[2 * jj];                                         \
          const uint2 g1 = G[2 * jj + 1];                                     \
          b00.u[jj] = __builtin_amdgcn_perm(g1.x, g0.x, 0x05040100u);         \
          b01.u[jj] = __builtin_amdgcn_perm(g1.x, g0.x, 0x07060302u);         \
          b10.u[jj] = __builtin_amdgcn_perm(g1.y, g0.y, 0x05040100u);         \
          b11.u[jj] = __builtin_amdgcn_perm(g1.y, g0.y, 0x07060302u);         \
      }                                                                       \
      _Pragma("unroll")                                                       \
      for (int p = 0; p < 2; p++) {                                           \
          _Pragma("unroll")                                                   \
          for (int hh2 = 0; hh2 < 2; hh2++) {                                 \
              const bf16x8 b = p ? (hh2 ? b11.v : b10.v)                      \
                                 : (hh2 ? b01.v : b00.v);                     \
              f32x4 o = {0.f, 0.f, 0.f, 0.f};                                 \
              o = __builtin_amdgcn_mfma_f32_16x16x32_bf16(af[EI].v, b, o, 0, 0, 0); \
              const int fc   = hh2 * 16 + low;                                \
              const int cblk = fc + (quad >> 1) * 32;                         \
              const int slot = ee_ ^ fc;                                      \
              const int hw   = p * 16384 + cblk * 256 + slot * 8 + (quad & 1) * 4; \
              uint2 ph;                                                       \
              ph.x = (unsigned int)f2bf(o[0]) | ((unsigned int)f2bf(o[1]) << 16); \
              ph.y = (unsigned int)f2bf(o[2]) | ((unsigned int)f2bf(o[3]) << 16); \
              *(uint2*)&wf2[hw] = ph;                                         \
          } } }

#define K2_GEMM(C2)                                                           \
    _Pragma("unroll")                                                         \
    for (int p = 0; p < 2; p++) {                                             \
        _Pragma("unroll 4")                                                   \
        for (int ktl = 0; ktl < 16; ktl++) {                                  \
            const int fc   = ktl * 2 + (quad >> 1);                           \
            const int cblk = fc + (quad & 1) * 32;                            \
            const int s0 = (low ^ fc) * 8;                                    \
            const int s1 = ((16 + low) ^ fc) * 8;                             \
            bf16x8 a0 = *(const bf16x8*)&wf2[p * 16384 + cblk * 256 + s0];    \
            bf16x8 a1 = *(const bf16x8*)&wf2[p * 16384 + cblk * 256 + s1];    \
            const int ktg = (2 * (C2) + p) * 16 + ktl;                        \
            bf16x8 b0 = Bp[(nt0 * 64 + ktg) * 64 + lane];                     \
            bf16x8 b1 = Bp[(nt1 * 64 + ktg) * 64 + lane];                     \
            acc00 = __builtin_amdgcn_mfma_f32_16x16x32_bf16(a0, b0, acc00, 0, 0, 0); \
            acc01 = __builtin_amdgcn_mfma_f32_16x16x32_bf16(a0, b1, acc01, 0, 0, 0); \
            acc10 = __builtin_amdgcn_mfma_f32_16x16x32_bf16(a1, b0, acc10, 0, 0, 0); \
            acc11 = __builtin_amdgcn_mfma_f32_16x16x32_bf16(a1, b1, acc11, 0, 0, 0); \
        } }

    // ---- issue first gather round, then hide it under the sqrt-heavy A-fragments ----
    K2_ISSUE(gqA, 0, 0)

    #pragma unroll
    for (int ei = 0; ei < 4; ei++) {
        const int ee = wave * 4 + ei;
        const float kx = dk_s[ee * 45 + kb + 0];
        const float ky = dk_s[ee * 45 + kb + 1];
        const float kz = dk_s[ee * 45 + kb + 2];
        #pragma unroll
        for (int j = 0; j < 8; j++) {
            const int ni = ee * 32 + quad * 8 + j;
            const float dx = relx[ni] - kx;
            const float dy = rely[ni] - ky;
            const float dz = relz[ni] - kz;
            const float d = sqrtf(dx * dx + dy * dy + dz * dz);
            float w = 1.0f - d * INV_EXT;
            w = (low < KPN && w > 0.f) ? w : 0.f;
            af[ei].u[j] = f2bf(w);
        }
    }
    K2_ISSUE(gqB, 1, 0)
    __syncthreads();   // rel/dk dead; wf2 free for tiles

    // ---- build c2=0 with rolling prefetch (last issue crosses into c2=1) ----
    K2_BUILD(gqA, 0)  K2_ISSUE(gqA, 2, 0)
    K2_BUILD(gqB, 1)  K2_ISSUE(gqB, 3, 0)
    K2_BUILD(gqA, 2)  K2_ISSUE(gqA, 0, 1)
    K2_BUILD(gqB, 3)
    __syncthreads();
    K2_GEMM(0)
    __syncthreads();

    // ---- build c2=1 (gqA holds unit (0,1) across GEMM(0)) ----
    K2_ISSUE(gqB, 1, 1)
    K2_BUILD(gqA, 0)  K2_ISSUE(gqA, 2, 1)
    K2_BUILD(gqB, 1)  K2_ISSUE(gqB, 3, 1)
    K2_BUILD(gqA, 2)
    K2_BUILD(gqB, 3)
    __syncthreads();
    K2_GEMM(1)

#undef K2_ISSUE
#undef K2_BUILD
#undef K2_GEMM

    #pragma unroll
    for (int r = 0; r < 4; r++) {
        const int e0 = quad * 4 + r;
        out[(qbase + e0) * FO + nt0 * 16 + low] = acc00[r];
        out[(qbase + e0) * FO + nt1 * 16 + low] = acc01[r];
        out[(qbase + 16 + e0) * FO + nt0 * 16 + low] = acc10[r];
        out[(qbase + 16 + e0) * FO + nt1 * 16 + low] = acc11[r];
    }
}

// -------------------------------------------------------------------------
extern "C" void kernel_launch(void* const* d_in, const int* in_sizes, int n_in,
                              void* d_out, int out_size, void* d_ws, size_t ws_size,
                              hipStream_t stream) {
    const float* query     = (const float*)d_in[0];
    const float* support   = (const float*)d_in[1];
    const int*   neighbors = (const int*)  d_in[2];
    const float* features  = (const float*)d_in[3];
    const float* kpoints   = (const float*)d_in[4];
    const float* weight    = (const float*)d_in[5];
    const float* dweight   = (const float*)d_in[6];
    const float* bias      = (const float*)d_in[7];
    float*       out       = (float*)d_out;

    char* ws = (char*)d_ws;
    unsigned int*   fp1  = (unsigned int*)(ws + WS_FP1);
    unsigned int*   fp2  = (unsigned int*)(ws + WS_FP2);
    unsigned short* Bsw  = (unsigned short*)(ws + WS_BSW);
    unsigned short* dwBh = (unsigned short*)(ws + WS_DWBH);
    unsigned short* dwBl = (unsigned short*)(ws + WS_DWBL);
    float*          defkp = (float*)(ws + WS_DEFKP);

    pre_all<<<1328, 256, 0, stream>>>(features, fp1, fp2, weight, Bsw,
                                      dweight, dwBh, dwBl);
    k1_offsets<<<NQ / 16, 512, 0, stream>>>(query, support, neighbors, fp1,
                                            kpoints, dwBh, dwBl, bias, defkp);
    k2_deform<<<NQ / 32, 512, 0, stream>>>(query, support, neighbors, fp2,
                                           Bsw, defkp, out);
}

// Round 9
// 163.033 us; speedup vs baseline: 1.0572x; 1.0053x over previous
//
#include <hip/hip_runtime.h>
#include <hip/hip_bf16.h>
#include <math.h>

typedef __attribute__((ext_vector_type(8))) short bf16x8;
typedef __attribute__((ext_vector_type(4))) float f32x4;

#define NQ 16384
#define NN 32
#define FI 128
#define FO 256
#define KPN 15
#define OD 42
#define INV_EXT 0.5f

// ws layout (bytes)
#define WS_FP1    0u                        // CHUNK-MAJOR [4][NQ][16 uint2] = 8 MB
#define WS_FP2    (8u * 1024u * 1024u)      // CHUNK-MAJOR [2][NQ][16 uint2] = 4 MB
#define WS_BSW    (12u * 1024u * 1024u)     // 1 MB
#define WS_DWBH   (13u * 1024u * 1024u)     // 196,608
#define WS_DWBL   (WS_DWBH + 196608u)       // 196,608
#define WS_DEFKP  (14u * 1024u * 1024u)     // 16384*45*4 = 2.95 MB

static __device__ __forceinline__ unsigned short f2bf(float x) {
    union { __hip_bfloat16 h; unsigned short u; } cv;
    cv.h = __float2bfloat16(x);
    return cv.u;
}
static __device__ __forceinline__ float bf2f(unsigned short h) {
    union { unsigned int u; float f; } cv;
    cv.u = ((unsigned int)h) << 16;
    return cv.f;
}

union U8 { unsigned short u[8]; bf16x8 v; };

// ------------------------- pre-kernel (chunk-major stores) -------------------------
// fp1 (chunk-major): uint2 at [c*NQ*16 + s*16 + low] = {hi(fA)|hi(fB), lo(fA)|lo(fB)},
//   fA = c*32+low, fB = c*32+16+low. Active gather slice per chunk = 2 MB (< 4 MB XCD L2).
// fp2 (chunk-major): uint2 at [c2*NQ*16 + s*16 + low] covers feature groups 2c2 (.x-pairs
//   interleave) exactly as before, just slice-major.
__global__ void pre_all(const float* __restrict__ feat,
                        unsigned int* __restrict__ fp1, unsigned int* __restrict__ fp2,
                        const float* __restrict__ w, unsigned short* __restrict__ Bsw,
                        const float* __restrict__ dw,
                        unsigned short* __restrict__ dhi, unsigned short* __restrict__ dlo)
{
    const int b = blockIdx.x, t = threadIdx.x;
    if (b < 1024) {
        const int g  = b * 256 + t;           // 262,144 = 16384 * 4fp * 4lq
        const int lq = g & 3;
        const int fp = (g >> 2) & 3;
        const int s  = g >> 4;
        const float4* f4 = (const float4*)feat;
        const float4 A = f4[s * 32 + fp * 8 + lq];       // f = fp*32 + lq*4 + e
        const float4 C = f4[s * 32 + fp * 8 + 4 + lq];   // f + 16
        const float av[4] = {A.x, A.y, A.z, A.w};
        const float cv[4] = {C.x, C.y, C.z, C.w};
        unsigned int pw[8];
        #pragma unroll
        for (int e = 0; e < 4; e++) {
            const unsigned short ha = f2bf(av[e]), hc = f2bf(cv[e]);
            const unsigned short la = f2bf(av[e] - bf2f(ha));
            const unsigned short lc = f2bf(cv[e] - bf2f(hc));
            pw[2 * e]     = (unsigned int)ha | ((unsigned int)hc << 16);
            pw[2 * e + 1] = (unsigned int)la | ((unsigned int)lc << 16);
            fp2[(fp >> 1) * (NQ * 32) + s * 32 + (lq * 4 + e) * 2 + (fp & 1)] =
                (unsigned int)ha | ((unsigned int)hc << 16);
        }
        *(uint4*)&fp1[fp * (NQ * 32) + s * 32 + lq * 8]     = *(uint4*)&pw[0];
        *(uint4*)&fp1[fp * (NQ * 32) + s * 32 + lq * 8 + 4] = *(uint4*)&pw[4];
    } else if (b < 1024 + 256) {
        const int tid = (b - 1024) * 256 + t; // 65536 total
        const int lane = tid & 63;
        const int kt   = (tid >> 6) & 63;
        const int nt   = tid >> 12;
        const int n    = nt * 16 + (lane & 15);
        const int kbase = kt * 32 + (lane >> 4) * 8;
        unsigned int p[4];
        #pragma unroll
        for (int jj = 0; jj < 4; jj++) {
            unsigned int lo, hi;
            {
                const int kk = kbase + 2 * jj;
                const int f = kk >> 4, k = kk & 15;
                lo = (k < KPN) ? f2bf(w[(k * FI + f) * FO + n]) : 0u;
            }
            {
                const int kk = kbase + 2 * jj + 1;
                const int f = kk >> 4, k = kk & 15;
                hi = (k < KPN) ? f2bf(w[(k * FI + f) * FO + n]) : 0u;
            }
            p[jj] = lo | (hi << 16);
        }
        unsigned int* op = (unsigned int*)&Bsw[tid * 8];
        op[0] = p[0]; op[1] = p[1]; op[2] = p[2]; op[3] = p[3];
    } else {
        const int tid = (b - 1280) * 256 + t; // 12288 total
        const int lane = tid & 63;
        const int kt   = (tid >> 6) & 63;
        const int nt   = tid >> 12;
        const int o    = nt * 16 + (lane & 15);
        const int kbase = kt * 32 + (lane >> 4) * 8;
        #pragma unroll
        for (int j = 0; j < 8; j++) {
            const int kf = kbase + j;
            const int f = kf >> 4, k = kf & 15;
            float v = (k < KPN && o < OD) ? dw[(k * FI + f) * OD + o] : 0.f;
            unsigned short h = f2bf(v);
            dhi[tid * 8 + j] = h;
            dlo[tid * 8 + j] = f2bf(v - bf2f(h));
        }
    }
}

// ------------------------- stage 1: offsets (R6 structure; chunk-major gathers) ----------
// LDS ~43.5 KB -> 3 blocks/CU. Conflict-free swizzle. Gathers now hit the 2 MB
// per-chunk fp1 slice -> L2-resident (was ~8x HBM re-fetch at row-major layout).
__global__ __launch_bounds__(512, 4)
void k1_offsets(const float* __restrict__ query, const float* __restrict__ support,
                const int* __restrict__ neighbors, const unsigned int* __restrict__ fp1,
                const float* __restrict__ kpoints,
                const unsigned short* __restrict__ dwB_hi,
                const unsigned short* __restrict__ dwB_lo,
                const float* __restrict__ bias, float* __restrict__ defkp)
{
    __shared__ unsigned short wf_hi[8192];              // 16 KB
    __shared__ unsigned short wf_lo[8192];              // 16 KB
    __shared__ float relx[512], rely[512], relz[512];   // 6 KB
    __shared__ int   nbr_s[512];                        // 2 KB
    __shared__ float kp_s[48];                          // 192 B
    __shared__ f32x4 cred[3 * 64];                      // 3 KB

    const int t = threadIdx.x;
    const int qbase = blockIdx.x * 16;
    if (t < 45) kp_s[t] = kpoints[t];
    if (t >= 45 && t < 48) kp_s[t] = 0.f;

    {   // 512 threads = 16 queries x 32 neighbors
        const int e = t >> 5, n = t & 31;
        const int q = qbase + e;
        const int idx = neighbors[q * NN + n];
        nbr_s[t] = idx;
        relx[t] = support[idx * 3 + 0] - query[q * 3 + 0];
        rely[t] = support[idx * 3 + 1] - query[q * 3 + 1];
        relz[t] = support[idx * 3 + 2] - query[q * 3 + 2];
    }
    __syncthreads();

    const int wave = t >> 6, lane = t & 63;
    const int quad = lane >> 4, low = lane & 15;
    const int kb = (low < KPN) ? low * 3 : 0;

    // A-fragments (split-bf16 w0^T), 2 queries per wave
    U8 ah[2], al[2];
    {
        const float kx = kp_s[kb + 0], ky = kp_s[kb + 1], kz = kp_s[kb + 2];
        #pragma unroll
        for (int ei = 0; ei < 2; ei++) {
            const int ee = wave * 2 + ei;
            #pragma unroll
            for (int j = 0; j < 8; j++) {
                const int ni = ee * 32 + quad * 8 + j;
                const float dx = relx[ni] - kx;
                const float dy = rely[ni] - ky;
                const float dz = relz[ni] - kz;
                const float d = sqrtf(dx * dx + dy * dy + dz * dz);
                float w = 1.0f - d * INV_EXT;
                w = (low < KPN && w > 0.f) ? w : 0.f;
                const unsigned short h = f2bf(w);
                ah[ei].u[j] = h;
                al[ei].u[j] = f2bf(w - bf2f(h));
            }
        }
    }

    f32x4 acc = {0.f, 0.f, 0.f, 0.f};
    const int nt = wave >> 1, half = wave & 1;   // phase-C: 3 o-tiles x 2 slice-halves
    const uint2* fp1v = (const uint2*)fp1;
    const bf16x8* Bh = (const bf16x8*)dwB_hi;
    const bf16x8* Bl = (const bf16x8*)dwB_lo;

    for (int c = 0; c < 4; c++) {
        const uint2* fp1c = fp1v + c * (NQ * 16);    // 2 MB chunk slice
        // ---- phase B: wf0 chunk (split hi/lo) ----
        #pragma unroll
        for (int ei = 0; ei < 2; ei++) {
            const int ee = wave * 2 + ei;
            union { unsigned int u[4]; bf16x8 v; } bhA, blA, bhB, blB;
            #pragma unroll
            for (int jj = 0; jj < 4; jj++) {
                const int r0 = nbr_s[ee * 32 + quad * 8 + 2 * jj];
                const int r1 = nbr_s[ee * 32 + quad * 8 + 2 * jj + 1];
                const uint2 d0 = fp1c[r0 * 16 + low];
                const uint2 d1 = fp1c[r1 * 16 + low];
                bhA.u[jj] = __builtin_amdgcn_perm(d1.x, d0.x, 0x05040100u);
                bhB.u[jj] = __builtin_amdgcn_perm(d1.x, d0.x, 0x07060302u);
                blA.u[jj] = __builtin_amdgcn_perm(d1.y, d0.y, 0x05040100u);
                blB.u[jj] = __builtin_amdgcn_perm(d1.y, d0.y, 0x07060302u);
            }
            #pragma unroll
            for (int hh2 = 0; hh2 < 2; hh2++) {
                const bf16x8 bh = hh2 ? bhB.v : bhA.v;
                const bf16x8 bl = hh2 ? blB.v : blA.v;
                f32x4 o = {0.f, 0.f, 0.f, 0.f};
                o = __builtin_amdgcn_mfma_f32_16x16x32_bf16(al[ei].v, bh, o, 0, 0, 0);
                o = __builtin_amdgcn_mfma_f32_16x16x32_bf16(ah[ei].v, bl, o, 0, 0, 0);
                o = __builtin_amdgcn_mfma_f32_16x16x32_bf16(ah[ei].v, bh, o, 0, 0, 0);
                const int fc   = hh2 * 16 + low;              // f within chunk
                const int cblk = fc + (quad >> 1) * 32;       // k>>3 = quad>>1
                const int slot = ee ^ (fc & 15);
                const int hw   = cblk * 128 + slot * 8 + (quad & 1) * 4;
                const unsigned short h0 = f2bf(o[0]), h1 = f2bf(o[1]);
                const unsigned short h2 = f2bf(o[2]), h3 = f2bf(o[3]);
                uint2 ph;
                ph.x = (unsigned int)h0 | ((unsigned int)h1 << 16);
                ph.y = (unsigned int)h2 | ((unsigned int)h3 << 16);
                *(uint2*)&wf_hi[hw] = ph;
                uint2 pl;
                pl.x = (unsigned int)f2bf(o[0] - bf2f(h0)) |
                       ((unsigned int)f2bf(o[1] - bf2f(h1)) << 16);
                pl.y = (unsigned int)f2bf(o[2] - bf2f(h2)) |
                       ((unsigned int)f2bf(o[3] - bf2f(h3)) << 16);
                *(uint2*)&wf_lo[hw] = pl;
            }
        }
        __syncthreads();
        // ---- phase C: feat0[16e x 48o] accumulate (6 waves) ----
        if (wave < 6) {
            #pragma unroll 4
            for (int ktl = half * 8; ktl < half * 8 + 8; ktl++) {
                const int fc   = ktl * 2 + (quad >> 1);
                const int cblk = fc + (quad & 1) * 32;        // k>>3 = quad&1
                const int slot = low ^ (fc & 15);
                const int hw   = cblk * 128 + slot * 8;
                bf16x8 a_h = *(const bf16x8*)&wf_hi[hw];
                bf16x8 a_l = *(const bf16x8*)&wf_lo[hw];
                const int ktg = c * 16 + ktl;
                bf16x8 b_h = Bh[(nt * 64 + ktg) * 64 + lane];
                bf16x8 b_l = Bl[(nt * 64 + ktg) * 64 + lane];
                acc = __builtin_amdgcn_mfma_f32_16x16x32_bf16(a_l, b_h, acc, 0, 0, 0);
                acc = __builtin_amdgcn_mfma_f32_16x16x32_bf16(a_h, b_l, acc, 0, 0, 0);
                acc = __builtin_amdgcn_mfma_f32_16x16x32_bf16(a_h, b_h, acc, 0, 0, 0);
            }
        } else if (c == 0 && wave == 6 && lane < 48) {
            defkp[(qbase + lane / 3) * 45 + (lane % 3)] = kp_s[lane % 3];
        }
        __syncthreads();
    }

    if (wave < 6 && half == 1) cred[nt * 64 + lane] = acc;
    __syncthreads();
    if (wave < 6 && half == 0) {
        f32x4 o2 = cred[nt * 64 + lane];
        acc[0] += o2[0]; acc[1] += o2[1]; acc[2] += o2[2]; acc[3] += o2[3];
        const int o = nt * 16 + low;
        if (o < OD) {
            const float bo = bias[o] + kp_s[3 + o];
            #pragma unroll
            for (int r = 0; r < 4; r++) {
                const int ee = quad * 4 + r;
                defkp[(qbase + ee) * 45 + 3 + o] = bo + acc[r];
            }
        }
    }
}

// ------------------------- stage 2: deformable conv (R8 pipeline; chunk-major gathers) ----
__global__ __launch_bounds__(512, 4)
void k2_deform(const float* __restrict__ query, const float* __restrict__ support,
               const int* __restrict__ neighbors, const unsigned int* __restrict__ fp2,
               const unsigned short* __restrict__ Bsw, const float* __restrict__ defkp,
               float* __restrict__ out)
{
    __shared__ unsigned short wf2[32768];                 // 64 KB (aliased below)
    __shared__ unsigned short nbr_s[1024];                // 2 KB

    float* relx = (float*)wf2;          // [0,1024)      4 KB
    float* rely = relx + 1024;          // [1024,2048)   4 KB
    float* relz = relx + 2048;          // [2048,3072)   4 KB
    float* dk_s = relx + 3072;          // [3072,4512)   5.76 KB  (all dead after prologue)

    const int t = threadIdx.x;
    const int qbase = blockIdx.x * 32;

    for (int i = t; i < 32 * 45; i += 512) dk_s[i] = defkp[qbase * 45 + i];
    #pragma unroll
    for (int ii = 0; ii < 2; ii++) {
        const int i = ii * 512 + t;
        const int e = i >> 5, n = i & 31;
        const int q = qbase + e;
        const int idx = neighbors[q * NN + n];
        nbr_s[i] = (unsigned short)idx;
        relx[i] = support[idx * 3 + 0] - query[q * 3 + 0];
        rely[i] = support[idx * 3 + 1] - query[q * 3 + 1];
        relz[i] = support[idx * 3 + 2] - query[q * 3 + 2];
    }
    __syncthreads();

    const int wave = t >> 6, lane = t & 63;
    const int quad = lane >> 4, low = lane & 15;
    const int kb = (low < KPN) ? low * 3 : 0;

    const uint2* fp2v = (const uint2*)fp2;
    const bf16x8* Bp = (const bf16x8*)Bsw;
    const int nt0 = wave * 2, nt1 = nt0 + 1;

    uint2 gqA[8], gqB[8];
    U8 af[4];
    f32x4 acc00 = {0,0,0,0}, acc01 = {0,0,0,0};
    f32x4 acc10 = {0,0,0,0}, acc11 = {0,0,0,0};

#define K2_ISSUE(G, EI, C2)                                                   \
    { const int ee_ = wave * 4 + (EI);                                        \
      const uint2* fp2c_ = fp2v + (C2) * (NQ * 16);                           \
      _Pragma("unroll")                                                       \
      for (int jj = 0; jj < 4; jj++) {                                        \
          const int r0 = nbr_s[ee_ * 32 + quad * 8 + 2 * jj];                 \
          const int r1 = nbr_s[ee_ * 32 + quad * 8 + 2 * jj + 1];             \
          G[2 * jj]     = fp2c_[r0 * 16 + low];                               \
          G[2 * jj + 1] = fp2c_[r1 * 16 + low];                               \
      } }

#define K2_BUILD(G, EI)                                                       \
    { const int ee_ = wave * 4 + (EI);                                        \
      union { unsigned int u[4]; bf16x8 v; } b00, b01, b10, b11;              \
      _Pragma("unroll")                                                       \
      for (int jj = 0; jj < 4; jj++) {                                        \
          const uint2 g0 = G[2 * jj];                                         \
          const uint2 g1 = G[2 * jj + 1];                                     \
          b00.u[jj] = __builtin_amdgcn_perm(g1.x, g0.x, 0x05040100u);         \
          b01.u[jj] = __builtin_amdgcn_perm(g1.x, g0.x, 0x07060302u);         \
          b10.u[jj] = __builtin_amdgcn_perm(g1.y, g0.y, 0x05040100u);         \
          b11.u[jj] = __builtin_amdgcn_perm(g1.y, g0.y, 0x07060302u);         \
      }                                                                       \
      _Pragma("unroll")                                                       \
      for (int p = 0; p < 2; p++) {                                           \
          _Pragma("unroll")                                                   \
          for (int hh2 = 0; hh2 < 2; hh2++) {                                 \
              const bf16x8 b = p ? (hh2 ? b11.v : b10.v)                      \
                                 : (hh2 ? b01.v : b00.v);                     \
              f32x4 o = {0.f, 0.f, 0.f, 0.f};                                 \
              o = __builtin_amdgcn_mfma_f32_16x16x32_bf16(af[EI].v, b, o, 0, 0, 0); \
              const int fc   = hh2 * 16 + low;                                \
              const int cblk = fc + (quad >> 1) * 32;                         \
              const int slot = ee_ ^ fc;                                      \
              const int hw   = p * 16384 + cblk * 256 + slot * 8 + (quad & 1) * 4; \
              uint2 ph;                                                       \
              ph.x = (unsigned int)f2bf(o[0]) | ((unsigned int)f2bf(o[1]) << 16); \
              ph.y = (unsigned int)f2bf(o[2]) | ((unsigned int)f2bf(o[3]) << 16); \
              *(uint2*)&wf2[hw] = ph;                                         \
          } } }

#define K2_GEMM(C2)                                                           \
    _Pragma("unroll")                                                         \
    for (int p = 0; p < 2; p++) {                                             \
        _Pragma("unroll 4")                                                   \
        for (int ktl = 0; ktl < 16; ktl++) {                                  \
            const int fc   = ktl * 2 + (quad >> 1);                           \
            const int cblk = fc + (quad & 1) * 32;                            \
            const int s0 = (low ^ fc) * 8;                                    \
            const int s1 = ((16 + low) ^ fc) * 8;                             \
            bf16x8 a0 = *(const bf16x8*)&wf2[p * 16384 + cblk * 256 + s0];    \
            bf16x8 a1 = *(const bf16x8*)&wf2[p * 16384 + cblk * 256 + s1];    \
            const int ktg = (2 * (C2) + p) * 16 + ktl;                        \
            bf16x8 b0 = Bp[(nt0 * 64 + ktg) * 64 + lane];                     \
            bf16x8 b1 = Bp[(nt1 * 64 + ktg) * 64 + lane];                     \
            acc00 = __builtin_amdgcn_mfma_f32_16x16x32_bf16(a0, b0, acc00, 0, 0, 0); \
            acc01 = __builtin_amdgcn_mfma_f32_16x16x32_bf16(a0, b1, acc01, 0, 0, 0); \
            acc10 = __builtin_amdgcn_mfma_f32_16x16x32_bf16(a1, b0, acc10, 0, 0, 0); \
            acc11 = __builtin_amdgcn_mfma_f32_16x16x32_bf16(a1, b1, acc11, 0, 0, 0); \
        } }

    // ---- issue first gather round, then hide it under the sqrt-heavy A-fragments ----
    K2_ISSUE(gqA, 0, 0)

    #pragma unroll
    for (int ei = 0; ei < 4; ei++) {
        const int ee = wave * 4 + ei;
        const float kx = dk_s[ee * 45 + kb + 0];
        const float ky = dk_s[ee * 45 + kb + 1];
        const float kz = dk_s[ee * 45 + kb + 2];
        #pragma unroll
        for (int j = 0; j < 8; j++) {
            const int ni = ee * 32 + quad * 8 + j;
            const float dx = relx[ni] - kx;
            const float dy = rely[ni] - ky;
            const float dz = relz[ni] - kz;
            const float d = sqrtf(dx * dx + dy * dy + dz * dz);
            float w = 1.0f - d * INV_EXT;
            w = (low < KPN && w > 0.f) ? w : 0.f;
            af[ei].u[j] = f2bf(w);
        }
    }
    K2_ISSUE(gqB, 1, 0)
    __syncthreads();   // rel/dk dead; wf2 free for tiles

    // ---- build c2=0 with rolling prefetch (last issue crosses into c2=1) ----
    K2_BUILD(gqA, 0)  K2_ISSUE(gqA, 2, 0)
    K2_BUILD(gqB, 1)  K2_ISSUE(gqB, 3, 0)
    K2_BUILD(gqA, 2)  K2_ISSUE(gqA, 0, 1)
    K2_BUILD(gqB, 3)
    __syncthreads();
    K2_GEMM(0)
    __syncthreads();

    // ---- build c2=1 (gqA holds unit (0,1) across GEMM(0)) ----
    K2_ISSUE(gqB, 1, 1)
    K2_BUILD(gqA, 0)  K2_ISSUE(gqA, 2, 1)
    K2_BUILD(gqB, 1)  K2_ISSUE(gqB, 3, 1)
    K2_BUILD(gqA, 2)
    K2_BUILD(gqB, 3)
    __syncthreads();
    K2_GEMM(1)

#undef K2_ISSUE
#undef K2_BUILD
#undef K2_GEMM

    #pragma unroll
    for (int r = 0; r < 4; r++) {
        const int e0 = quad * 4 + r;
        out[(qbase + e0) * FO + nt0 * 16 + low] = acc00[r];
        out[(qbase + e0) * FO + nt1 * 16 + low] = acc01[r];
        out[(qbase + 16 + e0) * FO + nt0 * 16 + low] = acc10[r];
        out[(qbase + 16 + e0) * FO + nt1 * 16 + low] = acc11[r];
    }
}

// -------------------------------------------------------------------------
extern "C" void kernel_launch(void* const* d_in, const int* in_sizes, int n_in,
                              void* d_out, int out_size, void* d_ws, size_t ws_size,
                              hipStream_t stream) {
    const float* query     = (const float*)d_in[0];
    const float* support   = (const float*)d_in[1];
    const int*   neighbors = (const int*)  d_in[2];
    const float* features  = (const float*)d_in[3];
    const float* kpoints   = (const float*)d_in[4];
    const float* weight    = (const float*)d_in[5];
    const float* dweight   = (const float*)d_in[6];
    const float* bias      = (const float*)d_in[7];
    float*       out       = (float*)d_out;

    char* ws = (char*)d_ws;
    unsigned int*   fp1  = (unsigned int*)(ws + WS_FP1);
    unsigned int*   fp2  = (unsigned int*)(ws + WS_FP2);
    unsigned short* Bsw  = (unsigned short*)(ws + WS_BSW);
    unsigned short* dwBh = (unsigned short*)(ws + WS_DWBH);
    unsigned short* dwBl = (unsigned short*)(ws + WS_DWBL);
    float*          defkp = (float*)(ws + WS_DEFKP);

    pre_all<<<1328, 256, 0, stream>>>(features, fp1, fp2, weight, Bsw,
                                      dweight, dwBh, dwBl);
    k1_offsets<<<NQ / 16, 512, 0, stream>>>(query, support, neighbors, fp1,
                                            kpoints, dwBh, dwBl, bias, defkp);
    k2_deform<<<NQ / 32, 512, 0, stream>>>(query, support, neighbors, fp2,
                                           Bsw, defkp, out);
}